// Round 9
// baseline (603.006 us; speedup 1.0000x reference)
//
#include <hip/hip_runtime.h>
#include <math.h>

typedef _Float16 f16x8 __attribute__((ext_vector_type(8)));
typedef float f32x4 __attribute__((ext_vector_type(4)));

#define CIN 8
#define HIN 128
#define WIN 128
#define OH 126
#define OW 126
#define COUT 64
#define NB 128
#define NGROUPS 16
#define CPG 4
#define PWN 31
#define XROWS 35   // max row touched: base(28)+dy(3)+ky(3)=34

// workspace layout
// f16 extremum plane [b][wy][wx][c] (c innermost) | f32 partials | int counters
#define NPOOL (NB*PWN*PWN*COUT)          // 7,872,512 f16 elements
#define OFF_PART (NPOOL/2)               // float offset; [b][g][tile16][{sum,sumsq}]
#define NPART (NB*NGROUPS*16*2)          // 65,536 floats
#define OFF_CNT (OFF_PART + NPART)       // 128 ints (one per batch)

// ws counters are 0xAA-poisoned by the harness before every call.
__global__ void zero_cnt_kernel(float* __restrict__ ws)
{
  ((int*)(ws + OFF_CNT))[threadIdx.x] = 0;
}

// Conv via MFMA implicit GEMM (R8-proven structure) + fused per-batch
// finalize: the 16th block of a batch to finish (device-scope atomic ticket,
// release/acquire via __threadfence) runs GN-stats + affine + clamp + NCHW
// transpose for that batch in-kernel. Eliminates the separate finalize
// dispatch (total-conv was a traffic-invariant ~93us across R4/R5/R8).
__global__ __launch_bounds__(256, 4)
void conv_mfma_kernel(const float* __restrict__ x,
                      const float* __restrict__ w,
                      const float* __restrict__ bias,
                      const float* __restrict__ gnw,
                      const float* __restrict__ gnb,
                      const float* __restrict__ scale,
                      float* __restrict__ ws,
                      float* __restrict__ out)
{
  __shared__ __align__(16) _Float16 xs[XROWS*34*8];   // 19,040 B (reused by finalize)
  __shared__ __align__(16) _Float16 wls[12*64*8];     // 12,288 B
  __shared__ float red[4][16][2];
  __shared__ int winner;

  const int tid  = threadIdx.x;
  const int lane = tid & 63, wave = tid >> 6;
  const int tileIdx = blockIdx.x;          // 0..15
  const int tx = tileIdx & 3, ty = tileIdx >> 2;
  const int b  = blockIdx.y;
  const int ox0 = tx*32, oy0 = ty*32;

  // ---- stage weights [khw][n][ci], khw>=9 zeroed ----
  for (int idx = tid; idx < 12*64*8; idx += 256) {
    const int ci = idx & 7, n = (idx >> 3) & 63, khw = idx >> 9;
    const float v = (khw < 9) ? w[(n*CIN + ci)*9 + khw] : 0.f;
    wls[idx] = (_Float16)v;
  }

  // ---- stage x tile: pack 8 ci -> one b128 write per pixel ----
  const float* xb = x + (size_t)b * CIN*HIN*WIN;
  for (int p = tid; p < XROWS*34; p += 256) {
    const int r = p / 34, c = p - r*34;
    const int iy = oy0 + r, ix = ox0 + c;
    const bool ok = (iy < HIN) && (ix < WIN);
    const int gbase = iy*WIN + ix;
    f16x8 pk;
    #pragma unroll
    for (int ci = 0; ci < 8; ++ci) {
      const float v = ok ? xb[ci*HIN*WIN + gbase] : 0.f;
      pk[ci] = (_Float16)v;
    }
    *(f16x8*)&xs[p*8] = pk;
  }
  __syncthreads();

  const int q = lane >> 4, ln = lane & 15;

  // B fragments: 4 ch-tiles x 3 K-chunks resident (48 VGPRs)
  f16x8 bf[4][3];
  #pragma unroll
  for (int nt = 0; nt < 4; ++nt)
    #pragma unroll
    for (int c = 0; c < 3; ++c)
      bf[nt][c] = *(const f16x8*)&wls[((c*4 + q)*64 + nt*16 + ln)*8];

  // per-lane A offsets (A lane map: m = lane&15 pixel, k-quad = lane>>4)
  const int dy = ln >> 2, dx = ln & 3;
  int aoff[3];
  #pragma unroll
  for (int c = 0; c < 3; ++c) {
    const int khw = c*4 + q;
    const int ky = khw / 3, kx = khw - 3*(khw/3);
    aoff[c] = ((dy + ky)*34 + (dx + kx))*8;
  }

  float bias_r[4], sgn[4];
  #pragma unroll
  for (int nt = 0; nt < 4; ++nt) {
    const int c = nt*16 + ln;
    bias_r[nt] = bias[c];
    sgn[nt] = (gnw[c]*scale[c] >= 0.f) ? 1.f : -1.f;  // GN slope sign (inv>0)
  }

  float s[4]  = {0.f,0.f,0.f,0.f};
  float sq[4] = {0.f,0.f,0.f,0.f};
  _Float16* wext = (_Float16*)ws;

  // 16 pool windows per wave (2 window-rows x 8 cols)
  #pragma unroll 2
  for (int i = 0; i < 16; ++i) {
    const int wyl = wave*2 + (i >> 3), wxl = i & 7;
    const int base = (wyl*4*34 + wxl*4)*8;

    f32x4 acc[4];
    #pragma unroll
    for (int nt = 0; nt < 4; ++nt) {
      const float bv = bias_r[nt];
      acc[nt] = (f32x4){bv, bv, bv, bv};   // bias as MFMA C operand
    }
    #pragma unroll
    for (int c = 0; c < 3; ++c) {
      const f16x8 a = *(const f16x8*)&xs[base + aoff[c]];
      #pragma unroll
      for (int nt = 0; nt < 4; ++nt)
        acc[nt] = __builtin_amdgcn_mfma_f32_16x16x32_f16(a, bf[nt][c], acc[nt], 0, 0, 0);
    }

    const int wyg = ty*8 + wyl, wxg = tx*8 + wxl;
    if ((wyg < PWN) && (wxg < PWN)) {
      const size_t rowbase = ((size_t)(b*PWN + wyg)*PWN + wxg)*COUT;
      float m4[4];
      #pragma unroll
      for (int nt = 0; nt < 4; ++nt) {
        const float v0 = acc[nt][0], v1 = acc[nt][1];
        const float v2 = acc[nt][2], v3 = acc[nt][3];
        s[nt]  += (v0+v1) + (v2+v3);
        sq[nt] += v0*v0 + v1*v1 + v2*v2 + v3*v3;
        const float sg = sgn[nt];
        float m = fmaxf(fmaxf(sg*v0, sg*v1), fmaxf(sg*v2, sg*v3));
        m = fmaxf(m, __shfl_xor(m, 16, 64));
        m = fmaxf(m, __shfl_xor(m, 32, 64));
        m4[nt] = sg*m;
      }
      // lane L stores channel c=L: pick m4[L>>4] -> one full-wave 128B store
      float mv = m4[0];
      mv = (q == 1) ? m4[1] : mv;
      mv = (q == 2) ? m4[2] : mv;
      mv = (q == 3) ? m4[3] : mv;
      wext[rowbase + lane] = (_Float16)mv;
    } else {
      // edge windows (wyg==31 or wxg==31): stats only, masked to 126x126
      const bool yv = (wyg*4 + q) < OH;
      #pragma unroll
      for (int nt = 0; nt < 4; ++nt) {
        #pragma unroll
        for (int r = 0; r < 4; ++r) {
          const bool okp = yv && (wxg*4 + r < OW);
          const float v = okp ? acc[nt][r] : 0.f;
          s[nt] += v; sq[nt] += v*v;
        }
      }
    }
  }

  // per-wave stat reduce: quads (xor 16,32) then channels-in-group (xor 1,2)
  #pragma unroll
  for (int nt = 0; nt < 4; ++nt) {
    float a = s[nt], c2 = sq[nt];
    a  += __shfl_xor(a, 16, 64);  a  += __shfl_xor(a, 32, 64);
    a  += __shfl_xor(a, 1, 64);   a  += __shfl_xor(a, 2, 64);
    c2 += __shfl_xor(c2, 16, 64); c2 += __shfl_xor(c2, 32, 64);
    c2 += __shfl_xor(c2, 1, 64);  c2 += __shfl_xor(c2, 2, 64);
    if (lane < 16 && (lane & 3) == 0) {
      red[wave][nt*4 + (ln >> 2)][0] = a;
      red[wave][nt*4 + (ln >> 2)][1] = c2;
    }
  }
  __syncthreads();
  if (tid < 32) {
    const int g = tid >> 1, k = tid & 1;
    const float t = red[0][g][k] + red[1][g][k] + red[2][g][k] + red[3][g][k];
    ws[OFF_PART + (((size_t)b*NGROUPS + g)*16 + tileIdx)*2 + k] = t;
  }

  // ---- per-batch arrival ticket (release: fence all stores, then atomic) ----
  __threadfence();          // device-scope release (buffer_wbl2 sc1 on gfx950)
  __syncthreads();
  if (tid == 0)
    winner = (atomicAdd((int*)(ws + OFF_CNT) + b, 1) == 15) ? 1 : 0;
  __syncthreads();
  if (!winner) return;
  __threadfence();          // acquire: invalidate caches before reading peers' data

  // ---- fused finalize for batch b (16th arriver only) ----
  float* fbuf = (float*)xs;            // As[64] | Bs[64] | vout[1984]
  float* As   = fbuf;
  float* Bs   = fbuf + 64;
  float* vout = fbuf + 128;            // [c][wx], stride 31 -> conflict-free
  float* stat_raw = (float*)red;       // 32 floats: [g][{sum,sumsq}]

  if (tid < 32) {
    const float* p = ws + OFF_PART + (size_t)(b*NGROUPS + (tid >> 1))*32 + (tid & 1);
    float acc0 = 0.f;
    #pragma unroll
    for (int t = 0; t < 16; ++t) acc0 += p[t*2];
    stat_raw[tid] = acc0;
  }
  __syncthreads();
  if (tid < COUT) {
    const int c = tid, g = c >> 2;
    const float N = (float)(CPG * OH * OW);
    const float mean = stat_raw[g*2] / N;
    const float var  = stat_raw[g*2 + 1] / N - mean*mean;
    const float inv  = rsqrtf(var + 1e-5f);
    const float ag   = inv * gnw[c];
    As[c] = ag * scale[c];
    Bs[c] = (gnb[c] - mean * ag) * scale[c];
  }
  __syncthreads();

  const _Float16* wextr = (const _Float16*)ws;
  for (int wy = 0; wy < PWN; ++wy) {
    const size_t rb = (size_t)(b*PWN + wy)*PWN*COUT;
    for (int idx = tid; idx < PWN*COUT; idx += 256) {
      const int c = idx & 63, wx = idx >> 6;
      float v = fmaf(As[c], (float)wextr[rb + idx], Bs[c]);
      v = fminf(fmaxf(v, 0.f), 1.f);
      vout[c*PWN + wx] = v;
    }
    __syncthreads();
    for (int idx = tid; idx < COUT*PWN; idx += 256) {
      const int c = idx / PWN, wx = idx - c*PWN;
      out[(((size_t)b*COUT + c)*PWN + wy)*PWN + wx] = vout[idx];
    }
    __syncthreads();   // protect vout before next wy overwrites
  }
}

extern "C" void kernel_launch(void* const* d_in, const int* in_sizes, int n_in,
                              void* d_out, int out_size, void* d_ws, size_t ws_size,
                              hipStream_t stream)
{
  const float* x     = (const float*)d_in[0];
  const float* cw    = (const float*)d_in[1];
  const float* cb    = (const float*)d_in[2];
  const float* gnw   = (const float*)d_in[3];
  const float* gnb   = (const float*)d_in[4];
  const float* scale = (const float*)d_in[5];
  float* out = (float*)d_out;
  float* ws  = (float*)d_ws;

  zero_cnt_kernel<<<1, NB, 0, stream>>>(ws);

  dim3 gridA(16, NB, 1);
  conv_mfma_kernel<<<gridA, 256, 0, stream>>>(x, cw, cb, gnw, gnb, scale, ws, out);
}

// Round 10
// 185.069 us; speedup vs baseline: 3.2583x; 3.2583x over previous
//
#include <hip/hip_runtime.h>
#include <math.h>

typedef _Float16 f16x8 __attribute__((ext_vector_type(8)));
typedef float f32x4 __attribute__((ext_vector_type(4)));

#define CIN 8
#define HIN 128
#define WIN 128
#define OH 126
#define OW 126
#define COUT 64
#define NB 128
#define NGROUPS 16
#define CPG 4
#define PWN 31
#define XROWS 34   // real taps reach row 28+3+2=33; padded khw>=9 clamped to 0

// workspace layout
// f16 ext plane [b][wy][wx][c] | f32 partials [b][g][tile16][{s,sq}] | f32 AB [b][{A64,B64}]
#define NPOOL (NB*PWN*PWN*COUT)          // 7,872,512 f16 elements
#define OFF_PART (NPOOL/2)               // float offset
#define NPART (NB*NGROUPS*16*2)
#define OFF_AB (OFF_PART + NPART)        // 128*128 floats

// Conv via MFMA implicit GEMM (R8-proven geometry).
// LDS cut to 27.7KB -> 5 blocks/CU (was 4 @32.25KB): xs 34 rows, wls 9 khw
// (padded khw 9..11 B-frags are all-zero -> synthesized in registers,
// their A-addresses clamped to 0: finite*0=0).
__global__ __launch_bounds__(256, 4)
void conv_mfma_kernel(const float* __restrict__ x,
                      const float* __restrict__ w,
                      const float* __restrict__ bias,
                      const float* __restrict__ gnw,
                      const float* __restrict__ scale,
                      float* __restrict__ ws)
{
  __shared__ __align__(16) _Float16 xs[XROWS*34*8];   // 18,496 B
  __shared__ __align__(16) _Float16 wls[9*64*8];      //  9,216 B
  __shared__ float red[4][16][2];

  const int tid  = threadIdx.x;
  const int lane = tid & 63, wave = tid >> 6;
  const int tileIdx = blockIdx.x;          // 0..15
  const int tx = tileIdx & 3, ty = tileIdx >> 2;
  const int b  = blockIdx.y;
  const int ox0 = tx*32, oy0 = ty*32;

  // ---- stage weights [khw 9][n 64][ci 8] ----
  for (int idx = tid; idx < 9*64*8; idx += 256) {
    const int ci = idx & 7, n = (idx >> 3) & 63, khw = idx >> 9;
    wls[idx] = (_Float16)w[(n*CIN + ci)*9 + khw];
  }

  // ---- stage x tile: pack 8 ci -> one b128 write per pixel ----
  const float* xb = x + (size_t)b * CIN*HIN*WIN;
  for (int p = tid; p < XROWS*34; p += 256) {
    const int r = p / 34, c = p - r*34;
    const int iy = oy0 + r, ix = ox0 + c;
    const bool ok = (iy < HIN) && (ix < WIN);
    const int gbase = iy*WIN + ix;
    f16x8 pk;
    #pragma unroll
    for (int ci = 0; ci < 8; ++ci) {
      const float v = ok ? xb[ci*HIN*WIN + gbase] : 0.f;
      pk[ci] = (_Float16)v;
    }
    *(f16x8*)&xs[p*8] = pk;
  }
  __syncthreads();

  const int q = lane >> 4, ln = lane & 15;

  // B fragments: chunks c=0,1 from LDS; c=2 is khw=8 for q==0, zero otherwise
  f16x8 bf[4][3];
  #pragma unroll
  for (int nt = 0; nt < 4; ++nt) {
    #pragma unroll
    for (int c = 0; c < 2; ++c)
      bf[nt][c] = *(const f16x8*)&wls[((c*4 + q)*64 + nt*16 + ln)*8];
    if (q == 0)
      bf[nt][2] = *(const f16x8*)&wls[((8)*64 + nt*16 + ln)*8];
    else
      bf[nt][2] = (f16x8){0,0,0,0,0,0,0,0};
  }

  // per-lane A offsets (A lane map: m = lane&15 pixel, k-quad = lane>>4)
  const int dy = ln >> 2, dx = ln & 3;
  int aoff[3];
  #pragma unroll
  for (int c = 0; c < 3; ++c) {
    const int khw = c*4 + q;               // 0..11
    const int ky = khw / 3, kx = khw - 3*(khw/3);
    aoff[c] = (khw < 9) ? ((dy + ky)*34 + (dx + kx))*8 : 0;  // clamp padded taps
  }

  float bias_r[4], sgn[4];
  #pragma unroll
  for (int nt = 0; nt < 4; ++nt) {
    const int c = nt*16 + ln;
    bias_r[nt] = bias[c];
    sgn[nt] = (gnw[c]*scale[c] >= 0.f) ? 1.f : -1.f;  // GN slope sign (inv>0)
  }

  float s[4]  = {0.f,0.f,0.f,0.f};
  float sq[4] = {0.f,0.f,0.f,0.f};
  _Float16* wext = (_Float16*)ws;

  // 16 pool windows per wave (2 window-rows x 8 cols)
  #pragma unroll 2
  for (int i = 0; i < 16; ++i) {
    const int wyl = wave*2 + (i >> 3), wxl = i & 7;
    const int base = (wyl*4*34 + wxl*4)*8;

    f32x4 acc[4];
    #pragma unroll
    for (int nt = 0; nt < 4; ++nt) {
      const float bv = bias_r[nt];
      acc[nt] = (f32x4){bv, bv, bv, bv};   // bias as MFMA C operand
    }
    #pragma unroll
    for (int c = 0; c < 3; ++c) {
      const f16x8 a = *(const f16x8*)&xs[base + aoff[c]];
      #pragma unroll
      for (int nt = 0; nt < 4; ++nt)
        acc[nt] = __builtin_amdgcn_mfma_f32_16x16x32_f16(a, bf[nt][c], acc[nt], 0, 0, 0);
    }

    const int wyg = ty*8 + wyl, wxg = tx*8 + wxl;
    if ((wyg < PWN) && (wxg < PWN)) {
      const size_t rowbase = ((size_t)(b*PWN + wyg)*PWN + wxg)*COUT;
      float m4[4];
      #pragma unroll
      for (int nt = 0; nt < 4; ++nt) {
        const float v0 = acc[nt][0], v1 = acc[nt][1];
        const float v2 = acc[nt][2], v3 = acc[nt][3];
        s[nt]  += (v0+v1) + (v2+v3);
        sq[nt] += v0*v0 + v1*v1 + v2*v2 + v3*v3;
        const float sg = sgn[nt];
        float m = fmaxf(fmaxf(sg*v0, sg*v1), fmaxf(sg*v2, sg*v3));
        m = fmaxf(m, __shfl_xor(m, 16, 64));
        m = fmaxf(m, __shfl_xor(m, 32, 64));
        m4[nt] = sg*m;
      }
      // lane L stores channel c=L: pick m4[L>>4] -> one full-wave 128B store
      float mv = m4[0];
      mv = (q == 1) ? m4[1] : mv;
      mv = (q == 2) ? m4[2] : mv;
      mv = (q == 3) ? m4[3] : mv;
      wext[rowbase + lane] = (_Float16)mv;
    } else {
      // edge windows (wyg==31 or wxg==31): stats only, masked to 126x126
      const bool yv = (wyg*4 + q) < OH;
      #pragma unroll
      for (int nt = 0; nt < 4; ++nt) {
        #pragma unroll
        for (int r = 0; r < 4; ++r) {
          const bool okp = yv && (wxg*4 + r < OW);
          const float v = okp ? acc[nt][r] : 0.f;
          s[nt] += v; sq[nt] += v*v;
        }
      }
    }
  }

  // per-wave stat reduce: quads (xor 16,32) then channels-in-group (xor 1,2)
  #pragma unroll
  for (int nt = 0; nt < 4; ++nt) {
    float a = s[nt], c2 = sq[nt];
    a  += __shfl_xor(a, 16, 64);  a  += __shfl_xor(a, 32, 64);
    a  += __shfl_xor(a, 1, 64);   a  += __shfl_xor(a, 2, 64);
    c2 += __shfl_xor(c2, 16, 64); c2 += __shfl_xor(c2, 32, 64);
    c2 += __shfl_xor(c2, 1, 64);  c2 += __shfl_xor(c2, 2, 64);
    if (lane < 16 && (lane & 3) == 0) {
      red[wave][nt*4 + (ln >> 2)][0] = a;
      red[wave][nt*4 + (ln >> 2)][1] = c2;
    }
  }
  __syncthreads();
  if (tid < 32) {
    const int g = tid >> 1, k = tid & 1;
    const float t = red[0][g][k] + red[1][g][k] + red[2][g][k] + red[3][g][k];
    ws[OFF_PART + (((size_t)b*NGROUPS + g)*16 + tileIdx)*2 + k] = t;
  }
}

// Per-batch GN stats -> per-channel affine (A,B) into ws. 128 blocks, L2-hot.
__global__ __launch_bounds__(64)
void prep_ab_kernel(const float* __restrict__ gnw,
                    const float* __restrict__ gnb,
                    const float* __restrict__ scale,
                    float* __restrict__ ws)
{
  __shared__ float stat[NGROUPS*2];   // [g][{sum,sumsq}]
  const int tid = threadIdx.x, b = blockIdx.x;
  if (tid < 32) {
    const int g = tid >> 1, k = tid & 1;
    const float* p = ws + OFF_PART + (size_t)(b*NGROUPS + g)*32 + k;
    float a = 0.f;
    #pragma unroll
    for (int t = 0; t < 16; ++t) a += p[t*2];
    stat[g*2 + k] = a;
  }
  __syncthreads();
  const int c = tid, g = c >> 2;
  const float N = (float)(CPG * OH * OW);
  const float mean = stat[g*2] / N;
  const float var  = stat[g*2 + 1] / N - mean*mean;
  const float inv  = rsqrtf(var + 1e-5f);
  const float ag   = inv * gnw[c];
  ws[OFF_AB + b*128 + c]      = ag * scale[c];
  ws[OFF_AB + b*128 + 64 + c] = (gnb[c] - mean * ag) * scale[c];
}

// Apply affine+clamp and transpose to NCHW. One block per (b, 4-row slab).
// No stats phase; f16x8 vector ext reads; LDS transpose; coalesced writes.
__global__ __launch_bounds__(256)
void apply_kernel(const float* __restrict__ ws, float* __restrict__ out)
{
  __shared__ float AB[128];
  __shared__ float vout[COUT*PWN];   // [c][wx], stride 31 -> conflict-free

  const int tid = threadIdx.x;
  const int yq  = blockIdx.x;   // 0..7 -> rows yq*4 .. yq*4+3 (skip >=31)
  const int b   = blockIdx.y;

  if (tid < 128) AB[tid] = ws[OFF_AB + b*128 + tid];
  __syncthreads();

  const _Float16* wext = (const _Float16*)ws;
  for (int r = 0; r < 4; ++r) {
    const int wy = yq*4 + r;
    if (wy >= PWN) break;
    const size_t rb = (size_t)(b*PWN + wy)*PWN*COUT;   // f16 elements

    if (tid < 248) {                       // 248*8 = 1984 ext elems
      const f16x8 e = *(const f16x8*)&wext[rb + tid*8];
      const int wx = tid >> 3, c0 = (tid & 7)*8;
      #pragma unroll
      for (int j = 0; j < 8; ++j) {
        const int c = c0 + j;
        float v = fmaf(AB[c], (float)e[j], AB[64 + c]);
        v = fminf(fmaxf(v, 0.f), 1.f);
        vout[c*PWN + wx] = v;
      }
    }
    __syncthreads();
    for (int e = tid; e < COUT*PWN; e += 256) {
      const int c = e / PWN, wx = e - c*PWN;
      out[(((size_t)b*COUT + c)*PWN + wy)*PWN + wx] = vout[e];
    }
    __syncthreads();
  }
}

extern "C" void kernel_launch(void* const* d_in, const int* in_sizes, int n_in,
                              void* d_out, int out_size, void* d_ws, size_t ws_size,
                              hipStream_t stream)
{
  const float* x     = (const float*)d_in[0];
  const float* cw    = (const float*)d_in[1];
  const float* cb    = (const float*)d_in[2];
  const float* gnw   = (const float*)d_in[3];
  const float* gnb   = (const float*)d_in[4];
  const float* scale = (const float*)d_in[5];
  float* out = (float*)d_out;
  float* ws  = (float*)d_ws;

  dim3 gridA(16, NB, 1);
  conv_mfma_kernel<<<gridA, 256, 0, stream>>>(x, cw, cb, gnw, scale, ws);

  prep_ab_kernel<<<NB, 64, 0, stream>>>(gnw, gnb, scale, ws);

  dim3 gridP(8, NB, 1);
  apply_kernel<<<gridP, 256, 0, stream>>>(ws, out);
}

// Round 11
// 182.771 us; speedup vs baseline: 3.2992x; 1.0126x over previous
//
#include <hip/hip_runtime.h>
#include <math.h>

typedef _Float16 f16x8 __attribute__((ext_vector_type(8)));
typedef float f32x4 __attribute__((ext_vector_type(4)));

#define CIN 8
#define HIN 128
#define WIN 128
#define OH 126
#define OW 126
#define COUT 64
#define NB 128
#define NGROUPS 16
#define CPG 4
#define PWN 31
#define XROWS 34   // real taps reach row 28+3+2=33; padded khw>=9 clamped to 0

// workspace layout
// f16 ext plane [b][wy][wx][c] | f32 partials [b][g][tile16][{s,sq}]
#define NPOOL (NB*PWN*PWN*COUT)          // 7,872,512 f16 elements
#define OFF_PART (NPOOL/2)               // float offset
#define NPART (NB*NGROUPS*16*2)

// Conv via MFMA implicit GEMM (R8/R10-proven geometry).
// __launch_bounds__(256,2): R10's (256,4) forced VGPR=64 < ~80 live values
// -> rematerialization bloat (4.8K VALU issue/wave vs ~2.5K static). LDS
// (28.2KB) caps residency at 5 blocks/CU anyway; ~102 VGPR keeps 5 waves/SIMD.
__global__ __launch_bounds__(256, 2)
void conv_mfma_kernel(const float* __restrict__ x,
                      const float* __restrict__ w,
                      const float* __restrict__ bias,
                      const float* __restrict__ gnw,
                      const float* __restrict__ scale,
                      float* __restrict__ ws)
{
  __shared__ __align__(16) _Float16 xs[XROWS*34*8];   // 18,496 B
  __shared__ __align__(16) _Float16 wls[9*64*8];      //  9,216 B
  __shared__ float red[4][16][2];

  const int tid  = threadIdx.x;
  const int lane = tid & 63, wave = tid >> 6;
  const int tileIdx = blockIdx.x;          // 0..15
  const int tx = tileIdx & 3, ty = tileIdx >> 2;
  const int b  = blockIdx.y;
  const int ox0 = tx*32, oy0 = ty*32;

  // ---- stage weights [khw 9][n 64][ci 8] ----
  for (int idx = tid; idx < 9*64*8; idx += 256) {
    const int ci = idx & 7, n = (idx >> 3) & 63, khw = idx >> 9;
    wls[idx] = (_Float16)w[(n*CIN + ci)*9 + khw];
  }

  // ---- stage x tile: pack 8 ci -> one b128 write per pixel ----
  const float* xb = x + (size_t)b * CIN*HIN*WIN;
  for (int p = tid; p < XROWS*34; p += 256) {
    const int r = p / 34, c = p - r*34;
    const int iy = oy0 + r, ix = ox0 + c;
    const bool ok = (iy < HIN) && (ix < WIN);
    const int gbase = iy*WIN + ix;
    f16x8 pk;
    #pragma unroll
    for (int ci = 0; ci < 8; ++ci) {
      const float v = ok ? xb[ci*HIN*WIN + gbase] : 0.f;
      pk[ci] = (_Float16)v;
    }
    *(f16x8*)&xs[p*8] = pk;
  }
  __syncthreads();

  const int q = lane >> 4, ln = lane & 15;

  // B fragments: chunks c=0,1 from LDS; c=2 is khw=8 for q==0, zero otherwise
  f16x8 bf[4][3];
  #pragma unroll
  for (int nt = 0; nt < 4; ++nt) {
    #pragma unroll
    for (int c = 0; c < 2; ++c)
      bf[nt][c] = *(const f16x8*)&wls[((c*4 + q)*64 + nt*16 + ln)*8];
    if (q == 0)
      bf[nt][2] = *(const f16x8*)&wls[((8)*64 + nt*16 + ln)*8];
    else
      bf[nt][2] = (f16x8){0,0,0,0,0,0,0,0};
  }

  // per-lane A offsets (A lane map: m = lane&15 pixel, k-quad = lane>>4)
  const int dy = ln >> 2, dx = ln & 3;
  int aoff[3];
  #pragma unroll
  for (int c = 0; c < 3; ++c) {
    const int khw = c*4 + q;               // 0..11
    const int ky = khw / 3, kx = khw - 3*(khw/3);
    aoff[c] = (khw < 9) ? ((dy + ky)*34 + (dx + kx))*8 : 0;  // clamp padded taps
  }

  float bias_r[4], sgn[4];
  #pragma unroll
  for (int nt = 0; nt < 4; ++nt) {
    const int c = nt*16 + ln;
    bias_r[nt] = bias[c];
    sgn[nt] = (gnw[c]*scale[c] >= 0.f) ? 1.f : -1.f;  // GN slope sign (inv>0)
  }

  float s[4]  = {0.f,0.f,0.f,0.f};
  float sq[4] = {0.f,0.f,0.f,0.f};
  _Float16* wext = (_Float16*)ws;

  // 16 pool windows per wave (2 window-rows x 8 cols)
  #pragma unroll 2
  for (int i = 0; i < 16; ++i) {
    const int wyl = wave*2 + (i >> 3), wxl = i & 7;
    const int base = (wyl*4*34 + wxl*4)*8;

    f32x4 acc[4];
    #pragma unroll
    for (int nt = 0; nt < 4; ++nt) {
      const float bv = bias_r[nt];
      acc[nt] = (f32x4){bv, bv, bv, bv};   // bias as MFMA C operand
    }
    #pragma unroll
    for (int c = 0; c < 3; ++c) {
      const f16x8 a = *(const f16x8*)&xs[base + aoff[c]];
      #pragma unroll
      for (int nt = 0; nt < 4; ++nt)
        acc[nt] = __builtin_amdgcn_mfma_f32_16x16x32_f16(a, bf[nt][c], acc[nt], 0, 0, 0);
    }

    const int wyg = ty*8 + wyl, wxg = tx*8 + wxl;
    if ((wyg < PWN) && (wxg < PWN)) {
      const size_t rowbase = ((size_t)(b*PWN + wyg)*PWN + wxg)*COUT;
      float m4[4];
      #pragma unroll
      for (int nt = 0; nt < 4; ++nt) {
        const float v0 = acc[nt][0], v1 = acc[nt][1];
        const float v2 = acc[nt][2], v3 = acc[nt][3];
        s[nt]  += (v0+v1) + (v2+v3);
        sq[nt] += v0*v0 + v1*v1 + v2*v2 + v3*v3;
        const float sg = sgn[nt];
        float m = fmaxf(fmaxf(sg*v0, sg*v1), fmaxf(sg*v2, sg*v3));
        m = fmaxf(m, __shfl_xor(m, 16, 64));
        m = fmaxf(m, __shfl_xor(m, 32, 64));
        m4[nt] = sg*m;
      }
      // lane L stores channel c=L: pick m4[L>>4] -> one full-wave 128B store
      float mv = m4[0];
      mv = (q == 1) ? m4[1] : mv;
      mv = (q == 2) ? m4[2] : mv;
      mv = (q == 3) ? m4[3] : mv;
      wext[rowbase + lane] = (_Float16)mv;
    } else {
      // edge windows (wyg==31 or wxg==31): stats only, masked to 126x126
      const bool yv = (wyg*4 + q) < OH;
      #pragma unroll
      for (int nt = 0; nt < 4; ++nt) {
        #pragma unroll
        for (int r = 0; r < 4; ++r) {
          const bool okp = yv && (wxg*4 + r < OW);
          const float v = okp ? acc[nt][r] : 0.f;
          s[nt] += v; sq[nt] += v*v;
        }
      }
    }
  }

  // per-wave stat reduce: quads (xor 16,32) then channels-in-group (xor 1,2)
  #pragma unroll
  for (int nt = 0; nt < 4; ++nt) {
    float a = s[nt], c2 = sq[nt];
    a  += __shfl_xor(a, 16, 64);  a  += __shfl_xor(a, 32, 64);
    a  += __shfl_xor(a, 1, 64);   a  += __shfl_xor(a, 2, 64);
    c2 += __shfl_xor(c2, 16, 64); c2 += __shfl_xor(c2, 32, 64);
    c2 += __shfl_xor(c2, 1, 64);  c2 += __shfl_xor(c2, 2, 64);
    if (lane < 16 && (lane & 3) == 0) {
      red[wave][nt*4 + (ln >> 2)][0] = a;
      red[wave][nt*4 + (ln >> 2)][1] = c2;
    }
  }
  __syncthreads();
  if (tid < 32) {
    const int g = tid >> 1, k = tid & 1;
    const float t = red[0][g][k] + red[1][g][k] + red[2][g][k] + red[3][g][k];
    ws[OFF_PART + (((size_t)b*NGROUPS + g)*16 + tileIdx)*2 + k] = t;
  }
}

// Fused tail: one kernel, 2048 independent blocks (b, xb). Each block
// redundantly computes its batch's GN affine from the L2-hot 1KB partials
// (no cross-block sync, no flags — R9's winner-serialization avoided),
// then applies affine+clamp+NCHW-transpose for 2 pooled rows.
__global__ __launch_bounds__(256)
void tail_kernel(const float* __restrict__ gnw,
                 const float* __restrict__ gnb,
                 const float* __restrict__ scale,
                 const float* __restrict__ ws,
                 float* __restrict__ out)
{
  __shared__ float stat[NGROUPS*2];   // [g][{sum,sumsq}]
  __shared__ float AB[128];           // A[64] | B[64]
  __shared__ float vout[COUT*PWN];    // [c][wx], stride 31 -> conflict-free

  const int tid = threadIdx.x;
  const int xb  = blockIdx.x;   // 0..15 -> rows 2*xb, 2*xb+1 (skip >=31)
  const int b   = blockIdx.y;

  if (tid < 32) {
    const int g = tid >> 1, k = tid & 1;
    const float* p = ws + OFF_PART + (size_t)(b*NGROUPS + g)*32 + k;
    float a = 0.f;
    #pragma unroll
    for (int t = 0; t < 16; ++t) a += p[t*2];
    stat[g*2 + k] = a;
  }
  __syncthreads();
  if (tid < COUT) {
    const int c = tid, g = c >> 2;
    const float N = (float)(CPG * OH * OW);
    const float mean = stat[g*2] / N;
    const float var  = stat[g*2 + 1] / N - mean*mean;
    const float inv  = rsqrtf(var + 1e-5f);
    const float ag   = inv * gnw[c];
    AB[c]      = ag * scale[c];
    AB[64 + c] = (gnb[c] - mean * ag) * scale[c];
  }
  __syncthreads();

  const _Float16* wext = (const _Float16*)ws;
  #pragma unroll
  for (int r = 0; r < 2; ++r) {
    const int wy = xb*2 + r;
    if (wy >= PWN) break;
    const size_t rb = (size_t)(b*PWN + wy)*PWN*COUT;   // f16 elements

    if (tid < 248) {                       // 248*8 = 1984 ext elems
      const f16x8 e = *(const f16x8*)&wext[rb + tid*8];
      const int wx = tid >> 3, c0 = (tid & 7)*8;
      #pragma unroll
      for (int j = 0; j < 8; ++j) {
        const int c = c0 + j;
        float v = fmaf(AB[c], (float)e[j], AB[64 + c]);
        v = fminf(fmaxf(v, 0.f), 1.f);
        vout[c*PWN + wx] = v;
      }
    }
    __syncthreads();
    for (int e = tid; e < COUT*PWN; e += 256) {
      const int c = e / PWN, wx = e - c*PWN;
      out[(((size_t)b*COUT + c)*PWN + wy)*PWN + wx] = vout[e];
    }
    __syncthreads();
  }
}

extern "C" void kernel_launch(void* const* d_in, const int* in_sizes, int n_in,
                              void* d_out, int out_size, void* d_ws, size_t ws_size,
                              hipStream_t stream)
{
  const float* x     = (const float*)d_in[0];
  const float* cw    = (const float*)d_in[1];
  const float* cb    = (const float*)d_in[2];
  const float* gnw   = (const float*)d_in[3];
  const float* gnb   = (const float*)d_in[4];
  const float* scale = (const float*)d_in[5];
  float* out = (float*)d_out;
  float* ws  = (float*)d_ws;

  dim3 gridA(16, NB, 1);
  conv_mfma_kernel<<<gridA, 256, 0, stream>>>(x, cw, cb, gnw, scale, ws);

  dim3 gridT(16, NB, 1);
  tail_kernel<<<gridT, 256, 0, stream>>>(gnw, gnb, scale, ws, out);
}